// Round 4
// baseline (170.488 us; speedup 1.0000x reference)
//
#include <hip/hip_runtime.h>
#include <hip/hip_bf16.h>

#define NPE 127

typedef short v8s __attribute__((ext_vector_type(8)));
typedef float v4f __attribute__((ext_vector_type(4)));
typedef float v2f __attribute__((ext_vector_type(2)));

// LDS float offsets (512-thread block = 8 waves = 8 nodes; HCJ shared per batch)
// Register history: unconstrained -> VGPR 64 arch + big AGPR segment (~160 total)
//   -> 3 waves/SIMD (36% occ). (512,8) -> scratch spill catastrophe (FETCH 847MB).
//   (512,4) -> neutral (hint doesn't constrain AGPR side).
// R4: loop-invariant weight state (~40 regs) moved to LDS broadcast table L_W,
//   re-read per tile (LICM defeated via asm-opaque offset) -> target <=128 total
//   regs -> 4 waves/SIMD. LDS 40720B stays under 40960 (4 blocks/CU).
#define L_HCJ 0       // 128 rows x 36
#define L_HCI 4608    // 8 nodes x 32
#define L_GR  4864    // 8 waves x 128 x 3 {r0*rinv, r1*rinv, r2*rinv}
#define L_GD  7936    // 8 waves x 128 x float2 {d2, ds2}
#define L_W   9984    // broadcast weights: EW1r64(32) EW1r65(32) AW(32) CW2(32) EB2(32) CB1(32) AB(1)
#define L_TOT 10180   // 40720 B

__device__ __forceinline__ float fast_rcp(float x){ return __builtin_amdgcn_rcpf(x); }
__device__ __forceinline__ float exp2_fast(float x){
#if __has_builtin(__builtin_amdgcn_exp2f)
    return __builtin_amdgcn_exp2f(x);
#else
    return exp2f(x);
#endif
}
#define LOG2E 1.44269504f
__device__ __forceinline__ float sigmoidf_(float x){
    return fast_rcp(1.0f + exp2_fast(-LOG2E * x));
}
__device__ __forceinline__ float tanhf_fast(float x){
    return fmaf(-2.0f, fast_rcp(1.0f + exp2_fast(2.0f * LOG2E * x)), 1.0f);
}
__device__ __forceinline__ v2f splat2(float v){ v2f r; r.x = v; r.y = v; return r; }
// packed-f32 silu: fma/add/mul lower to v_pk_*; exp/rcp stay scalar (per-element)
__device__ __forceinline__ v2f silu2(v2f x){
    v2f t = x * splat2(-LOG2E);
    v2f e; e.x = exp2_fast(t.x); e.y = exp2_fast(t.y);
    v2f d = e + splat2(1.0f);
    v2f r; r.x = fast_rcp(d.x); r.y = fast_rcp(d.y);
    return x * r;
}
__device__ __forceinline__ short f2bf(float x){
    __hip_bfloat16 h = __float2bfloat16(x);
    return *reinterpret_cast<short*>(&h);
}
union f4u { float4 f4; v2f v2[2]; float f[4]; };

__global__ __launch_bounds__(512, 4)
void eq_gnn_fused(const float* __restrict__ X, const float* __restrict__ Hin,
                  const float* __restrict__ DS,
                  const float* __restrict__ EW1, const float* __restrict__ EB1,
                  const float* __restrict__ EW2, const float* __restrict__ EB2,
                  const float* __restrict__ NW1, const float* __restrict__ NB1,
                  const float* __restrict__ NW2, const float* __restrict__ NB2,
                  const float* __restrict__ CW1, const float* __restrict__ CB1,
                  const float* __restrict__ CW2,
                  const float* __restrict__ AW,  const float* __restrict__ AB,
                  float* __restrict__ OUT)
{
    __shared__ float sm[L_TOT];
    const int tid  = threadIdx.x;
    const int lane = tid & 63;
    const int wid  = tid >> 6;           // 0..7
    const int m16  = lane & 15;
    const int q    = lane >> 4;
    const int bI   = blockIdx.x >> 4;    // batch
    const int grp  = blockIdx.x & 15;
    const int i    = grp * 8 + wid;      // this wave's node
    const int node = bI * 128 + i;

    // ---------- prologue W: broadcast weight table ----------
    if (tid < 193){
        float v;
        if (tid < 64)       v = EW1[64*32 + tid];        // rows 64,65
        else if (tid < 96)  v = AW[tid - 64];
        else if (tid < 128) v = CW2[tid - 96];
        else if (tid < 160) v = EB2[tid - 128];
        else if (tid < 192) v = CB1[tid - 160];
        else                v = AB[0];
        sm[L_W + tid] = v;
    }

    // ---------- prologue A: HCj[row][o] = h[row]@W1[32:64]; each wave does 16 rows ----------
    {
        v8s Aj0, Aj1;   // A = W1j^T : A[m=o][k] = W1[32+k][o]
        #pragma unroll
        for (int jj = 0; jj < 8; ++jj){
            Aj0[jj] = f2bf(EW1[(32 + q*8 + jj) * 32 + m16]);
            Aj1[jj] = f2bf(EW1[(32 + q*8 + jj) * 32 + 16 + m16]);
        }
        const int row = wid * 16 + m16;
        const float* hp = &Hin[(bI * 128 + row) * 32 + q * 8];
        const float4 h0 = *(const float4*)&hp[0];
        const float4 h1 = *(const float4*)&hp[4];
        v8s Bh;
        Bh[0]=f2bf(h0.x); Bh[1]=f2bf(h0.y); Bh[2]=f2bf(h0.z); Bh[3]=f2bf(h0.w);
        Bh[4]=f2bf(h1.x); Bh[5]=f2bf(h1.y); Bh[6]=f2bf(h1.z); Bh[7]=f2bf(h1.w);
        v4f d0 = {0.f,0.f,0.f,0.f}, d1 = {0.f,0.f,0.f,0.f};
        d0 = __builtin_amdgcn_mfma_f32_16x16x32_bf16(Aj0, Bh, d0, 0, 0, 0);
        d1 = __builtin_amdgcn_mfma_f32_16x16x32_bf16(Aj1, Bh, d1, 0, 0, 0);
        #pragma unroll
        for (int r = 0; r < 4; ++r){
            sm[L_HCJ + row * 36 + q*4 + r]      = d0[r];
            sm[L_HCJ + row * 36 + 16 + q*4 + r] = d1[r];
        }
    }
    // ---------- prologue B: hci (i-half + bias) for the block's 8 nodes ----------
    if (tid < 256){
        const int nl = tid >> 5, o = tid & 31;
        const float* hp = &Hin[(bI * 128 + grp * 8 + nl) * 32];
        float acc = EB1[o];
        #pragma unroll
        for (int k = 0; k < 32; ++k) acc = fmaf(hp[k], EW1[k * 32 + o], acc);
        sm[L_HCI + nl * 32 + o] = acc;
    }
    // ---------- prologue C: per-wave geometry, lane = edge ----------
    float* sgr = &sm[L_GR + wid * 384];   // stride-3 per edge
    float* sgd = &sm[L_GD + wid * 256];   // float2 per edge
    const float xi0 = X[bI*384 + i*3 + 0];
    const float xi1 = X[bI*384 + i*3 + 1];
    const float xi2 = X[bI*384 + i*3 + 2];
    #pragma unroll
    for (int p = 0; p < 2; ++p){
        const int slot = lane + 64 * p;
        const int js = (slot < NPE) ? slot : 126;
        const int j = js + ((js >= i) ? 1 : 0);
        const float* xj = &X[bI*384 + j*3];
        const float r0 = xi0 - xj[0], r1 = xi1 - xj[1], r2 = xi2 - xj[2];
        const float d2 = fmaf(r0, r0, fmaf(r1, r1, fmaf(r2, r2, 1e-6f)));
        const float d  = sqrtf(d2);
        const float rinv = fast_rcp(d + 1.0f);
        const float dsv = DS[bI*16256 + i*127 + js];
        sgr[slot*3 + 0] = r0 * rinv;
        sgr[slot*3 + 1] = r1 * rinv;
        sgr[slot*3 + 2] = r2 * rinv;
        *(float2*)&sgd[slot*2] = make_float2(d2, dsv * dsv);
    }
    __syncthreads();

    // ---------- persistent per-lane MFMA A-fragments (kept in regs) ----------
    v8s Aw20, Aw21, Ac0, Ac1;
    #pragma unroll
    for (int jj = 0; jj < 8; ++jj){
        Aw20[jj] = f2bf(EW2[(q*8 + jj) * 32 + m16]);
        Aw21[jj] = f2bf(EW2[(q*8 + jj) * 32 + 16 + m16]);
        const int tau = (jj < 4) ? (q*4 + jj) : (16 + q*4 + (jj - 4));
        Ac0[jj] = f2bf(CW1[tau * 32 + m16]);
        Ac1[jj] = f2bf(CW1[tau * 32 + 16 + m16]);
    }

    v2f ms2[4];
    #pragma unroll
    for (int g = 0; g < 4; ++g) ms2[g] = splat2(0.f);
    float xc0 = 0.f, xc1 = 0.f, xc2 = 0.f;

    // ---------- edge loop: 8 tiles x 16 edges ----------
    int wofs = 0;    // asm-opaqued each iteration to defeat LICM of LDS weight reads
    #pragma unroll 1
    for (int tl = 0; tl < 8; ++tl){
        asm volatile("" : "+v"(wofs));
        const int e = tl * 16 + m16;
        const float valid = (e < NPE) ? 1.f : 0.f;
        const int js = (e < NPE) ? e : 126;
        const int j = js + ((js >= i) ? 1 : 0);

        const float2 dd = *(const float2*)&sgd[e*2];
        f4u hjA, hjB;
        hjA.f4 = *(const float4*)&sm[L_HCJ + j*36 + q*8];
        hjB.f4 = *(const float4*)&sm[L_HCJ + j*36 + q*8 + 4];
        const v2f d2s  = splat2(dd.x);
        const v2f ds2s = splat2(dd.y);

        // phase-local broadcast weight reads (transient lifetime)
        f4u w64a, w64b, w65a, w65b, hcia, hcib;
        w64a.f4 = *(const float4*)&sm[L_W + wofs + q*8];
        w64b.f4 = *(const float4*)&sm[L_W + wofs + q*8 + 4];
        w65a.f4 = *(const float4*)&sm[L_W + wofs + 32 + q*8];
        w65b.f4 = *(const float4*)&sm[L_W + wofs + 32 + q*8 + 4];
        hcia.f4 = *(const float4*)&sm[L_HCI + wofs + wid*32 + q*8];
        hcib.f4 = *(const float4*)&sm[L_HCI + wofs + wid*32 + q*8 + 4];

        // t1 (B-frag slots k=q*8+jj), packed-f32 chains
        v2f t01, t23, t45, t67;
        {
            v2f z;
            z = hcia.v2[0] + hjA.v2[0];
            z = __builtin_elementwise_fma(d2s, w64a.v2[0], z);
            z = __builtin_elementwise_fma(ds2s, w65a.v2[0], z);
            t01 = silu2(z);
            z = hcia.v2[1] + hjA.v2[1];
            z = __builtin_elementwise_fma(d2s, w64a.v2[1], z);
            z = __builtin_elementwise_fma(ds2s, w65a.v2[1], z);
            t23 = silu2(z);
            z = hcib.v2[0] + hjB.v2[0];
            z = __builtin_elementwise_fma(d2s, w64b.v2[0], z);
            z = __builtin_elementwise_fma(ds2s, w65b.v2[0], z);
            t45 = silu2(z);
            z = hcib.v2[1] + hjB.v2[1];
            z = __builtin_elementwise_fma(d2s, w64b.v2[1], z);
            z = __builtin_elementwise_fma(ds2s, w65b.v2[1], z);
            t67 = silu2(z);
        }
        v8s Bt;
        Bt[0]=f2bf(t01.x); Bt[1]=f2bf(t01.y); Bt[2]=f2bf(t23.x); Bt[3]=f2bf(t23.y);
        Bt[4]=f2bf(t45.x); Bt[5]=f2bf(t45.y); Bt[6]=f2bf(t67.x); Bt[7]=f2bf(t67.y);

        // layer 2: D[f][e]  (C init = bias from LDS)
        f4u b2a, b2b;
        b2a.f4 = *(const float4*)&sm[L_W + wofs + 128 + q*4];
        b2b.f4 = *(const float4*)&sm[L_W + wofs + 128 + 16 + q*4];
        v4f c0 = {b2a.f[0], b2a.f[1], b2a.f[2], b2a.f[3]};
        v4f c1 = {b2b.f[0], b2b.f[1], b2b.f[2], b2b.f[3]};
        c0 = __builtin_amdgcn_mfma_f32_16x16x32_bf16(Aw20, Bt, c0, 0, 0, 0);
        c1 = __builtin_amdgcn_mfma_f32_16x16x32_bf16(Aw21, Bt, c1, 0, 0, 0);
        v2f sa, sb, sc, sd;
        { v2f z; z.x=c0[0]; z.y=c0[1]; sa = silu2(z); }
        { v2f z; z.x=c0[2]; z.y=c0[3]; sb = silu2(z); }
        { v2f z; z.x=c1[0]; z.y=c1[1]; sc = silu2(z); }
        { v2f z; z.x=c1[2]; z.y=c1[3]; sd = silu2(z); }

        // attention gate (C-space ordering)
        f4u awa, awb;
        awa.f4 = *(const float4*)&sm[L_W + wofs + 64 + q*4];
        awb.f4 = *(const float4*)&sm[L_W + wofs + 64 + 16 + q*4];
        v2f lgv = sa * awa.v2[0];
        lgv = __builtin_elementwise_fma(sb, awa.v2[1], lgv);
        lgv = __builtin_elementwise_fma(sc, awb.v2[0], lgv);
        lgv = __builtin_elementwise_fma(sd, awb.v2[1], lgv);
        float lg = lgv.x + lgv.y;
        lg += __shfl_xor(lg, 16, 64);
        lg += __shfl_xor(lg, 32, 64);
        const float ab0 = sm[L_W + wofs + 192];
        const float att = sigmoidf_(lg + ab0) * valid;
        const v2f atts = splat2(att);

        const v2f g0 = sa * atts, g1 = sb * atts, g2 = sc * atts, g3 = sd * atts;
        ms2[0] += g0; ms2[1] += g1; ms2[2] += g2; ms2[3] += g3;
        v8s Bm;
        Bm[0]=f2bf(g0.x); Bm[1]=f2bf(g0.y); Bm[2]=f2bf(g1.x); Bm[3]=f2bf(g1.y);
        Bm[4]=f2bf(g2.x); Bm[5]=f2bf(g2.y); Bm[6]=f2bf(g3.x); Bm[7]=f2bf(g3.y);

        // coord head (C init = bias from LDS)
        f4u cba, cbb;
        cba.f4 = *(const float4*)&sm[L_W + wofs + 160 + q*4];
        cbb.f4 = *(const float4*)&sm[L_W + wofs + 160 + 16 + q*4];
        v4f e0 = {cba.f[0], cba.f[1], cba.f[2], cba.f[3]};
        v4f e1 = {cbb.f[0], cbb.f[1], cbb.f[2], cbb.f[3]};
        e0 = __builtin_amdgcn_mfma_f32_16x16x32_bf16(Ac0, Bm, e0, 0, 0, 0);
        e1 = __builtin_amdgcn_mfma_f32_16x16x32_bf16(Ac1, Bm, e1, 0, 0, 0);
        v2f ca, cb, cc, cd;
        { v2f z; z.x=e0[0]; z.y=e0[1]; ca = silu2(z); }
        { v2f z; z.x=e0[2]; z.y=e0[3]; cb = silu2(z); }
        { v2f z; z.x=e1[0]; z.y=e1[1]; cc = silu2(z); }
        { v2f z; z.x=e1[2]; z.y=e1[3]; cd = silu2(z); }
        f4u cwa, cwb;
        cwa.f4 = *(const float4*)&sm[L_W + wofs + 96 + q*4];
        cwb.f4 = *(const float4*)&sm[L_W + wofs + 96 + 16 + q*4];
        v2f trv = ca * cwa.v2[0];
        trv = __builtin_elementwise_fma(cb, cwa.v2[1], trv);
        trv = __builtin_elementwise_fma(cc, cwb.v2[0], trv);
        trv = __builtin_elementwise_fma(cd, cwb.v2[1], trv);
        float tr = trv.x + trv.y;
        tr += __shfl_xor(tr, 16, 64);
        tr += __shfl_xor(tr, 32, 64);

        // r pre-scaled by rinv in prologue; just mask and accumulate
        const float coef = tanhf_fast(tr) * valid;
        const float rs0 = sgr[e*3 + 0];
        const float rs1 = sgr[e*3 + 1];
        const float rs2 = sgr[e*3 + 2];
        xc0 = fmaf(rs0, coef, xc0);
        xc1 = fmaf(rs1, coef, xc1);
        xc2 = fmaf(rs2, coef, xc2);
    }

    // ---------- reduce ms over the 16 edge-lanes within each quad ----------
    float msv[8] = {ms2[0].x, ms2[0].y, ms2[1].x, ms2[1].y,
                    ms2[2].x, ms2[2].y, ms2[3].x, ms2[3].y};
    #pragma unroll
    for (int jj = 0; jj < 8; ++jj){
        float v = msv[jj];
        v += __shfl_xor(v, 1, 64); v += __shfl_xor(v, 2, 64);
        v += __shfl_xor(v, 4, 64); v += __shfl_xor(v, 8, 64);
        msv[jj] = v;
    }
    // ---------- reduce xc over all 64 lanes (each edge counted 4x) ----------
    {
        float v0 = xc0, v1 = xc1, v2 = xc2;
        #pragma unroll
        for (int s = 1; s < 64; s <<= 1){
            v0 += __shfl_xor(v0, s, 64);
            v1 += __shfl_xor(v1, s, 64);
            v2 += __shfl_xor(v2, s, 64);
        }
        xc0 = v0 * 0.25f; xc1 = v1 * 0.25f; xc2 = v2 * 0.25f;
    }

    if (lane < 3){
        const float xiv = (lane == 0) ? xi0 : ((lane == 1) ? xi1 : xi2);
        const float xcv = (lane == 0) ? xc0 : ((lane == 1) ? xc1 : xc2);
        OUT[bI*384 + i*3 + lane] = fmaf(xcv, 5.0f, xiv);
    }

    // ---------- stash ms (feature-ordered) into now-free geometry LDS ----------
    if (m16 == 0){
        #pragma unroll
        for (int jj = 0; jj < 8; ++jj){
            const int tau = (jj < 4) ? (q*4 + jj) : (16 + q*4 + (jj - 4));
            sgr[tau] = msv[jj];
        }
    }

    // ---------- node MLP ----------
    const int o = lane & 31;
    const float* hp = &Hin[node * 32];
    float a1 = NB1[o];
    #pragma unroll
    for (int k = 0; k < 32; ++k) a1 = fmaf(hp[k], NW1[k * 32 + o], a1);
    #pragma unroll
    for (int k = 0; k < 32; ++k) a1 = fmaf(sgr[k], NW1[(32 + k) * 32 + o], a1);
    const float s1v = a1 * sigmoidf_(a1);
    float a2 = NB2[o];
    #pragma unroll
    for (int k = 0; k < 32; ++k) a2 = fmaf(__shfl(s1v, k, 64), NW2[k * 32 + o], a2);
    if (lane < 32)
        OUT[49152 + node * 32 + o] = hp[o] + a2;
}

extern "C" void kernel_launch(void* const* d_in, const int* in_sizes, int n_in,
                              void* d_out, int out_size, void* d_ws, size_t ws_size,
                              hipStream_t stream) {
    (void)in_sizes; (void)n_in; (void)out_size; (void)d_ws; (void)ws_size;
    eq_gnn_fused<<<dim3(2048), dim3(512), 0, stream>>>(
        (const float*)d_in[0],  (const float*)d_in[1],  (const float*)d_in[2],
        (const float*)d_in[3],  (const float*)d_in[4],  (const float*)d_in[5],  (const float*)d_in[6],
        (const float*)d_in[7],  (const float*)d_in[8],  (const float*)d_in[9],  (const float*)d_in[10],
        (const float*)d_in[11], (const float*)d_in[12], (const float*)d_in[13],
        (const float*)d_in[14], (const float*)d_in[15],
        (float*)d_out);
}

// Round 6
// 167.239 us; speedup vs baseline: 1.0194x; 1.0194x over previous
//
#include <hip/hip_runtime.h>
#include <hip/hip_bf16.h>

#define NPE 127

typedef short v8s __attribute__((ext_vector_type(8)));
typedef float v4f __attribute__((ext_vector_type(4)));
typedef float v2f __attribute__((ext_vector_type(2)));

// LDS float offsets (512-thread block = 8 waves = 8 nodes; HCJ shared per batch)
// History: R0 158.7us base (44KB LDS). R1 (512,8) reg-budget 64 -> spill disaster.
// R2 39936B LDS, no hint: 82.3us, occ 36%. R3 (512,4): neutral. R4 LDS weight
// table: 95.5us REGRESSION (more instrs, occ unchanged) -> reverted.
// R5: kernel is issue/latency-bound at fixed ~3 waves/SIMD; ~45% stall from one
// serial chain per tile. Fix = 2-tile ILP: 4 pair-iterations, transient state
// duplicated [2], phases unrolled so two independent chains interleave.
// (R5 bench was an infra failure — container acquisition; resubmitting as-is.)
#define L_HCJ 0       // 128 rows x 36
#define L_HCI 4608    // 8 nodes x 32
#define L_GR  4864    // 8 waves x 128 x 3 {r0*rinv, r1*rinv, r2*rinv}
#define L_GD  7936    // 8 waves x 128 x float2 {d2, ds2}
#define L_TOT 9984    // 39936 B -> 4 blocks/CU by LDS

__device__ __forceinline__ float fast_rcp(float x){ return __builtin_amdgcn_rcpf(x); }
__device__ __forceinline__ float exp2_fast(float x){
#if __has_builtin(__builtin_amdgcn_exp2f)
    return __builtin_amdgcn_exp2f(x);
#else
    return exp2f(x);
#endif
}
#define LOG2E 1.44269504f
__device__ __forceinline__ float sigmoidf_(float x){
    return fast_rcp(1.0f + exp2_fast(-LOG2E * x));
}
__device__ __forceinline__ float tanhf_fast(float x){
    return fmaf(-2.0f, fast_rcp(1.0f + exp2_fast(2.0f * LOG2E * x)), 1.0f);
}
__device__ __forceinline__ v2f splat2(float v){ v2f r; r.x = v; r.y = v; return r; }
// packed-f32 silu: fma/add/mul lower to v_pk_*; exp/rcp stay scalar (per-element)
__device__ __forceinline__ v2f silu2(v2f x){
    v2f t = x * splat2(-LOG2E);
    v2f e; e.x = exp2_fast(t.x); e.y = exp2_fast(t.y);
    v2f d = e + splat2(1.0f);
    v2f r; r.x = fast_rcp(d.x); r.y = fast_rcp(d.y);
    return x * r;
}
__device__ __forceinline__ short f2bf(float x){
    __hip_bfloat16 h = __float2bfloat16(x);
    return *reinterpret_cast<short*>(&h);
}
union f4u { float4 f4; v2f v2[2]; float f[4]; };

__global__ __launch_bounds__(512)
void eq_gnn_fused(const float* __restrict__ X, const float* __restrict__ Hin,
                  const float* __restrict__ DS,
                  const float* __restrict__ EW1, const float* __restrict__ EB1,
                  const float* __restrict__ EW2, const float* __restrict__ EB2,
                  const float* __restrict__ NW1, const float* __restrict__ NB1,
                  const float* __restrict__ NW2, const float* __restrict__ NB2,
                  const float* __restrict__ CW1, const float* __restrict__ CB1,
                  const float* __restrict__ CW2,
                  const float* __restrict__ AW,  const float* __restrict__ AB,
                  float* __restrict__ OUT)
{
    __shared__ float sm[L_TOT];
    const int tid  = threadIdx.x;
    const int lane = tid & 63;
    const int wid  = tid >> 6;           // 0..7
    const int m16  = lane & 15;
    const int q    = lane >> 4;
    const int bI   = blockIdx.x >> 4;    // batch
    const int grp  = blockIdx.x & 15;
    const int i    = grp * 8 + wid;      // this wave's node
    const int node = bI * 128 + i;

    // ---------- prologue A: HCj[row][o] = h[row]@W1[32:64]; each wave does 16 rows ----------
    {
        v8s Aj0, Aj1;   // A = W1j^T : A[m=o][k] = W1[32+k][o]
        #pragma unroll
        for (int jj = 0; jj < 8; ++jj){
            Aj0[jj] = f2bf(EW1[(32 + q*8 + jj) * 32 + m16]);
            Aj1[jj] = f2bf(EW1[(32 + q*8 + jj) * 32 + 16 + m16]);
        }
        const int row = wid * 16 + m16;
        const float* hp = &Hin[(bI * 128 + row) * 32 + q * 8];
        const float4 h0 = *(const float4*)&hp[0];
        const float4 h1 = *(const float4*)&hp[4];
        v8s Bh;
        Bh[0]=f2bf(h0.x); Bh[1]=f2bf(h0.y); Bh[2]=f2bf(h0.z); Bh[3]=f2bf(h0.w);
        Bh[4]=f2bf(h1.x); Bh[5]=f2bf(h1.y); Bh[6]=f2bf(h1.z); Bh[7]=f2bf(h1.w);
        v4f d0 = {0.f,0.f,0.f,0.f}, d1 = {0.f,0.f,0.f,0.f};
        d0 = __builtin_amdgcn_mfma_f32_16x16x32_bf16(Aj0, Bh, d0, 0, 0, 0);
        d1 = __builtin_amdgcn_mfma_f32_16x16x32_bf16(Aj1, Bh, d1, 0, 0, 0);
        #pragma unroll
        for (int r = 0; r < 4; ++r){
            sm[L_HCJ + row * 36 + q*4 + r]      = d0[r];
            sm[L_HCJ + row * 36 + 16 + q*4 + r] = d1[r];
        }
    }
    // ---------- prologue B: hci (i-half + bias) for the block's 8 nodes ----------
    if (tid < 256){
        const int nl = tid >> 5, o = tid & 31;
        const float* hp = &Hin[(bI * 128 + grp * 8 + nl) * 32];
        float acc = EB1[o];
        #pragma unroll
        for (int k = 0; k < 32; ++k) acc = fmaf(hp[k], EW1[k * 32 + o], acc);
        sm[L_HCI + nl * 32 + o] = acc;
    }
    // ---------- prologue C: per-wave geometry, lane = edge ----------
    float* sgr = &sm[L_GR + wid * 384];   // stride-3 per edge
    float* sgd = &sm[L_GD + wid * 256];   // float2 per edge
    const float xi0 = X[bI*384 + i*3 + 0];
    const float xi1 = X[bI*384 + i*3 + 1];
    const float xi2 = X[bI*384 + i*3 + 2];
    #pragma unroll
    for (int p = 0; p < 2; ++p){
        const int slot = lane + 64 * p;
        const int js = (slot < NPE) ? slot : 126;
        const int j = js + ((js >= i) ? 1 : 0);
        const float* xj = &X[bI*384 + j*3];
        const float r0 = xi0 - xj[0], r1 = xi1 - xj[1], r2 = xi2 - xj[2];
        const float d2 = fmaf(r0, r0, fmaf(r1, r1, fmaf(r2, r2, 1e-6f)));
        const float d  = sqrtf(d2);
        const float rinv = fast_rcp(d + 1.0f);
        const float dsv = DS[bI*16256 + i*127 + js];
        sgr[slot*3 + 0] = r0 * rinv;
        sgr[slot*3 + 1] = r1 * rinv;
        sgr[slot*3 + 2] = r2 * rinv;
        *(float2*)&sgd[slot*2] = make_float2(d2, dsv * dsv);
    }
    __syncthreads();

    // ---------- persistent per-lane weight fragments ----------
    v8s Aw20, Aw21, Ac0, Ac1;
    #pragma unroll
    for (int jj = 0; jj < 8; ++jj){
        Aw20[jj] = f2bf(EW2[(q*8 + jj) * 32 + m16]);
        Aw21[jj] = f2bf(EW2[(q*8 + jj) * 32 + 16 + m16]);
        const int tau = (jj < 4) ? (q*4 + jj) : (16 + q*4 + (jj - 4));
        Ac0[jj] = f2bf(CW1[tau * 32 + m16]);
        Ac1[jj] = f2bf(CW1[tau * 32 + 16 + m16]);
    }
    f4u w64a, w64b, w65a, w65b, hcia, hcib, awa, awb, cwa, cwb;
    w64a.f4 = *(const float4*)&EW1[64*32 + q*8];
    w64b.f4 = *(const float4*)&EW1[64*32 + q*8 + 4];
    w65a.f4 = *(const float4*)&EW1[65*32 + q*8];
    w65b.f4 = *(const float4*)&EW1[65*32 + q*8 + 4];
    hcia.f4 = *(const float4*)&sm[L_HCI + wid*32 + q*8];
    hcib.f4 = *(const float4*)&sm[L_HCI + wid*32 + q*8 + 4];
    awa.f4  = *(const float4*)&AW[q*4];        // C-space: features q*4+r
    awb.f4  = *(const float4*)&AW[16 + q*4];
    cwa.f4  = *(const float4*)&CW2[q*4];
    cwb.f4  = *(const float4*)&CW2[16 + q*4];
    const float4 b2A = *(const float4*)&EB2[q*4];
    const float4 b2B = *(const float4*)&EB2[16 + q*4];
    const float4 cbA = *(const float4*)&CB1[q*4];
    const float4 cbB = *(const float4*)&CB1[16 + q*4];
    const float ab0 = AB[0];

    v2f ms2[4];
    #pragma unroll
    for (int g = 0; g < 4; ++g) ms2[g] = splat2(0.f);
    float xc0 = 0.f, xc1 = 0.f, xc2 = 0.f;

    // ---------- edge loop: 4 pair-iterations x 2 tiles x 16 edges ----------
    // Two independent chains per iteration; phase loops unrolled so the
    // scheduler interleaves them (MFMA of A under silu of B, shfl of A under
    // t1 of B), hiding trans/DS/MFMA latency without extra waves.
    #pragma unroll 1
    for (int tp = 0; tp < 4; ++tp){
        float2 ddv[2]; f4u hjA[2], hjB[2]; float validv[2]; int ev[2];
        #pragma unroll
        for (int u = 0; u < 2; ++u){
            const int e = (tp*2 + u)*16 + m16;
            ev[u] = e;
            validv[u] = (e < NPE) ? 1.f : 0.f;
            const int js = (e < NPE) ? e : 126;
            const int j = js + ((js >= i) ? 1 : 0);
            ddv[u] = *(const float2*)&sgd[e*2];
            hjA[u].f4 = *(const float4*)&sm[L_HCJ + j*36 + q*8];
            hjB[u].f4 = *(const float4*)&sm[L_HCJ + j*36 + q*8 + 4];
        }

        // t1 (B-frag slots k=q*8+jj), packed-f32 chains, both tiles
        v8s Bt[2];
        #pragma unroll
        for (int u = 0; u < 2; ++u){
            const v2f d2s  = splat2(ddv[u].x);
            const v2f ds2s = splat2(ddv[u].y);
            v2f z, t01, t23, t45, t67;
            z = hcia.v2[0] + hjA[u].v2[0];
            z = __builtin_elementwise_fma(d2s, w64a.v2[0], z);
            z = __builtin_elementwise_fma(ds2s, w65a.v2[0], z);
            t01 = silu2(z);
            z = hcia.v2[1] + hjA[u].v2[1];
            z = __builtin_elementwise_fma(d2s, w64a.v2[1], z);
            z = __builtin_elementwise_fma(ds2s, w65a.v2[1], z);
            t23 = silu2(z);
            z = hcib.v2[0] + hjB[u].v2[0];
            z = __builtin_elementwise_fma(d2s, w64b.v2[0], z);
            z = __builtin_elementwise_fma(ds2s, w65b.v2[0], z);
            t45 = silu2(z);
            z = hcib.v2[1] + hjB[u].v2[1];
            z = __builtin_elementwise_fma(d2s, w64b.v2[1], z);
            z = __builtin_elementwise_fma(ds2s, w65b.v2[1], z);
            t67 = silu2(z);
            Bt[u][0]=f2bf(t01.x); Bt[u][1]=f2bf(t01.y); Bt[u][2]=f2bf(t23.x); Bt[u][3]=f2bf(t23.y);
            Bt[u][4]=f2bf(t45.x); Bt[u][5]=f2bf(t45.y); Bt[u][6]=f2bf(t67.x); Bt[u][7]=f2bf(t67.y);
        }

        // layer 2: D[f][e], both tiles back-to-back
        v4f c0[2], c1[2];
        #pragma unroll
        for (int u = 0; u < 2; ++u){
            v4f a = {b2A.x, b2A.y, b2A.z, b2A.w};
            v4f b = {b2B.x, b2B.y, b2B.z, b2B.w};
            c0[u] = __builtin_amdgcn_mfma_f32_16x16x32_bf16(Aw20, Bt[u], a, 0, 0, 0);
            c1[u] = __builtin_amdgcn_mfma_f32_16x16x32_bf16(Aw21, Bt[u], b, 0, 0, 0);
        }
        v2f sa[2], sb[2], sc[2], sd[2];
        #pragma unroll
        for (int u = 0; u < 2; ++u){
            { v2f z; z.x=c0[u][0]; z.y=c0[u][1]; sa[u] = silu2(z); }
            { v2f z; z.x=c0[u][2]; z.y=c0[u][3]; sb[u] = silu2(z); }
            { v2f z; z.x=c1[u][0]; z.y=c1[u][1]; sc[u] = silu2(z); }
            { v2f z; z.x=c1[u][2]; z.y=c1[u][3]; sd[u] = silu2(z); }
        }

        // attention gate (C-space ordering), both tiles
        float att[2];
        #pragma unroll
        for (int u = 0; u < 2; ++u){
            v2f lgv = sa[u] * awa.v2[0];
            lgv = __builtin_elementwise_fma(sb[u], awa.v2[1], lgv);
            lgv = __builtin_elementwise_fma(sc[u], awb.v2[0], lgv);
            lgv = __builtin_elementwise_fma(sd[u], awb.v2[1], lgv);
            float lg = lgv.x + lgv.y;
            lg += __shfl_xor(lg, 16, 64);
            lg += __shfl_xor(lg, 32, 64);
            att[u] = sigmoidf_(lg + ab0) * validv[u];
        }

        v8s Bm[2];
        #pragma unroll
        for (int u = 0; u < 2; ++u){
            const v2f atts = splat2(att[u]);
            const v2f g0 = sa[u] * atts, g1 = sb[u] * atts, g2 = sc[u] * atts, g3 = sd[u] * atts;
            ms2[0] += g0; ms2[1] += g1; ms2[2] += g2; ms2[3] += g3;
            Bm[u][0]=f2bf(g0.x); Bm[u][1]=f2bf(g0.y); Bm[u][2]=f2bf(g1.x); Bm[u][3]=f2bf(g1.y);
            Bm[u][4]=f2bf(g2.x); Bm[u][5]=f2bf(g2.y); Bm[u][6]=f2bf(g3.x); Bm[u][7]=f2bf(g3.y);
        }

        // coord head, both tiles
        v4f e0[2], e1[2];
        #pragma unroll
        for (int u = 0; u < 2; ++u){
            v4f a = {cbA.x, cbA.y, cbA.z, cbA.w};
            v4f b = {cbB.x, cbB.y, cbB.z, cbB.w};
            e0[u] = __builtin_amdgcn_mfma_f32_16x16x32_bf16(Ac0, Bm[u], a, 0, 0, 0);
            e1[u] = __builtin_amdgcn_mfma_f32_16x16x32_bf16(Ac1, Bm[u], b, 0, 0, 0);
        }
        #pragma unroll
        for (int u = 0; u < 2; ++u){
            v2f ca, cb, cc, cd;
            { v2f z; z.x=e0[u][0]; z.y=e0[u][1]; ca = silu2(z); }
            { v2f z; z.x=e0[u][2]; z.y=e0[u][3]; cb = silu2(z); }
            { v2f z; z.x=e1[u][0]; z.y=e1[u][1]; cc = silu2(z); }
            { v2f z; z.x=e1[u][2]; z.y=e1[u][3]; cd = silu2(z); }
            v2f trv = ca * cwa.v2[0];
            trv = __builtin_elementwise_fma(cb, cwa.v2[1], trv);
            trv = __builtin_elementwise_fma(cc, cwb.v2[0], trv);
            trv = __builtin_elementwise_fma(cd, cwb.v2[1], trv);
            float tr = trv.x + trv.y;
            tr += __shfl_xor(tr, 16, 64);
            tr += __shfl_xor(tr, 32, 64);

            // r pre-scaled by rinv in prologue; mask and accumulate
            const float coef = tanhf_fast(tr) * validv[u];
            const float rs0 = sgr[ev[u]*3 + 0];
            const float rs1 = sgr[ev[u]*3 + 1];
            const float rs2 = sgr[ev[u]*3 + 2];
            xc0 = fmaf(rs0, coef, xc0);
            xc1 = fmaf(rs1, coef, xc1);
            xc2 = fmaf(rs2, coef, xc2);
        }
    }

    // ---------- reduce ms over the 16 edge-lanes within each quad ----------
    float msv[8] = {ms2[0].x, ms2[0].y, ms2[1].x, ms2[1].y,
                    ms2[2].x, ms2[2].y, ms2[3].x, ms2[3].y};
    #pragma unroll
    for (int jj = 0; jj < 8; ++jj){
        float v = msv[jj];
        v += __shfl_xor(v, 1, 64); v += __shfl_xor(v, 2, 64);
        v += __shfl_xor(v, 4, 64); v += __shfl_xor(v, 8, 64);
        msv[jj] = v;
    }
    // ---------- reduce xc over all 64 lanes (each edge counted 4x) ----------
    {
        float v0 = xc0, v1 = xc1, v2 = xc2;
        #pragma unroll
        for (int s = 1; s < 64; s <<= 1){
            v0 += __shfl_xor(v0, s, 64);
            v1 += __shfl_xor(v1, s, 64);
            v2 += __shfl_xor(v2, s, 64);
        }
        xc0 = v0 * 0.25f; xc1 = v1 * 0.25f; xc2 = v2 * 0.25f;
    }

    if (lane < 3){
        const float xiv = (lane == 0) ? xi0 : ((lane == 1) ? xi1 : xi2);
        const float xcv = (lane == 0) ? xc0 : ((lane == 1) ? xc1 : xc2);
        OUT[bI*384 + i*3 + lane] = fmaf(xcv, 5.0f, xiv);
    }

    // ---------- stash ms (feature-ordered) into now-free geometry LDS ----------
    if (m16 == 0){
        #pragma unroll
        for (int jj = 0; jj < 8; ++jj){
            const int tau = (jj < 4) ? (q*4 + jj) : (16 + q*4 + (jj - 4));
            sgr[tau] = msv[jj];
        }
    }

    // ---------- node MLP ----------
    const int o = lane & 31;
    const float* hp = &Hin[node * 32];
    float a1 = NB1[o];
    #pragma unroll
    for (int k = 0; k < 32; ++k) a1 = fmaf(hp[k], NW1[k * 32 + o], a1);
    #pragma unroll
    for (int k = 0; k < 32; ++k) a1 = fmaf(sgr[k], NW1[(32 + k) * 32 + o], a1);
    const float s1v = a1 * sigmoidf_(a1);
    float a2 = NB2[o];
    #pragma unroll
    for (int k = 0; k < 32; ++k) a2 = fmaf(__shfl(s1v, k, 64), NW2[k * 32 + o], a2);
    if (lane < 32)
        OUT[49152 + node * 32 + o] = hp[o] + a2;
}

extern "C" void kernel_launch(void* const* d_in, const int* in_sizes, int n_in,
                              void* d_out, int out_size, void* d_ws, size_t ws_size,
                              hipStream_t stream) {
    (void)in_sizes; (void)n_in; (void)out_size; (void)d_ws; (void)ws_size;
    eq_gnn_fused<<<dim3(2048), dim3(512), 0, stream>>>(
        (const float*)d_in[0],  (const float*)d_in[1],  (const float*)d_in[2],
        (const float*)d_in[3],  (const float*)d_in[4],  (const float*)d_in[5],  (const float*)d_in[6],
        (const float*)d_in[7],  (const float*)d_in[8],  (const float*)d_in[9],  (const float*)d_in[10],
        (const float*)d_in[11], (const float*)d_in[12], (const float*)d_in[13],
        (const float*)d_in[14], (const float*)d_in[15],
        (float*)d_out);
}

// Round 7
// 164.174 us; speedup vs baseline: 1.0385x; 1.0187x over previous
//
#include <hip/hip_runtime.h>
#include <hip/hip_bf16.h>

#define NPE 127

typedef short v8s __attribute__((ext_vector_type(8)));
typedef float v4f __attribute__((ext_vector_type(4)));
typedef float v2f __attribute__((ext_vector_type(2)));

// LDS float offsets (512-thread block = 8 waves = 8 nodes; HCJ shared per batch)
// History: R2 82.3us = best (39936B LDS, no hints, VGPR 64 + ~100 AGPR -> 3 waves/SIMD).
// R1 (512,8): spill disaster. R3 (512,4): neutral. R4 LDS weight table: -13%.
// R6 2-tile ILP: crossed 170-reg boundary -> 2 waves/SIMD, -7%. Conclusion: sits
// exactly at 3-wave reg boundary; occupancy/ILP levers dead.
// R7: trans-pipe saturation theory (3 waves x 52 trans x 8cy ~ 104% of pipe).
// silu4: shared-rcp across 4 elements -> trans 8->5 per quad (52->34 per tile),
// +7 VALU. Single-variable change on R2 base.
#define L_HCJ 0       // 128 rows x 36
#define L_HCI 4608    // 8 nodes x 32
#define L_GR  4864    // 8 waves x 128 x 3 {r0*rinv, r1*rinv, r2*rinv}
#define L_GD  7936    // 8 waves x 128 x float2 {d2, ds2}
#define L_TOT 9984    // 39936 B -> 4 blocks/CU by LDS

__device__ __forceinline__ float fast_rcp(float x){ return __builtin_amdgcn_rcpf(x); }
__device__ __forceinline__ float exp2_fast(float x){
#if __has_builtin(__builtin_amdgcn_exp2f)
    return __builtin_amdgcn_exp2f(x);
#else
    return exp2f(x);
#endif
}
#define LOG2E 1.44269504f
__device__ __forceinline__ float sigmoidf_(float x){
    return fast_rcp(1.0f + exp2_fast(-LOG2E * x));
}
__device__ __forceinline__ float tanhf_fast(float x){
    return fmaf(-2.0f, fast_rcp(1.0f + exp2_fast(2.0f * LOG2E * x)), 1.0f);
}
__device__ __forceinline__ v2f splat2(float v){ v2f r; r.x = v; r.y = v; return r; }
// 4-element silu with ONE shared rcp: silu(z_i) = z_i / (1+exp(-z_i)).
// d_i = 1+exp2(-z_i*log2e); r = rcp(d0*d1*d2*d3); each output uses the
// exclusive-product trick. Trans: 4 exp + 1 rcp (vs 4 exp + 4 rcp).
// Safe: |z| <~ 12 for this data -> product <= ~7e20 << fp32 max.
__device__ __forceinline__ void silu4(v2f za, v2f zb, v2f &oa, v2f &ob){
    v2f ta = za * splat2(-LOG2E);
    v2f tb = zb * splat2(-LOG2E);
    float e0 = exp2_fast(ta.x), e1 = exp2_fast(ta.y);
    float e2 = exp2_fast(tb.x), e3 = exp2_fast(tb.y);
    v2f da = splat2(1.0f); da.x += e0; da.y += e1;
    v2f db = splat2(1.0f); db.x += e2; db.y += e3;
    const float s  = da.x * da.y;
    const float t  = db.x * db.y;
    const float r  = fast_rcp(s * t);
    const float qa = r * t;   // 1/(da.x*da.y)
    const float qb = r * s;   // 1/(db.x*db.y)
    v2f dswa; dswa.x = da.y; dswa.y = da.x;
    v2f dswb; dswb.x = db.y; dswb.y = db.x;
    oa = za * dswa * splat2(qa);
    ob = zb * dswb * splat2(qb);
}
__device__ __forceinline__ short f2bf(float x){
    __hip_bfloat16 h = __float2bfloat16(x);
    return *reinterpret_cast<short*>(&h);
}
union f4u { float4 f4; v2f v2[2]; float f[4]; };

__global__ __launch_bounds__(512)
void eq_gnn_fused(const float* __restrict__ X, const float* __restrict__ Hin,
                  const float* __restrict__ DS,
                  const float* __restrict__ EW1, const float* __restrict__ EB1,
                  const float* __restrict__ EW2, const float* __restrict__ EB2,
                  const float* __restrict__ NW1, const float* __restrict__ NB1,
                  const float* __restrict__ NW2, const float* __restrict__ NB2,
                  const float* __restrict__ CW1, const float* __restrict__ CB1,
                  const float* __restrict__ CW2,
                  const float* __restrict__ AW,  const float* __restrict__ AB,
                  float* __restrict__ OUT)
{
    __shared__ float sm[L_TOT];
    const int tid  = threadIdx.x;
    const int lane = tid & 63;
    const int wid  = tid >> 6;           // 0..7
    const int m16  = lane & 15;
    const int q    = lane >> 4;
    const int bI   = blockIdx.x >> 4;    // batch
    const int grp  = blockIdx.x & 15;
    const int i    = grp * 8 + wid;      // this wave's node
    const int node = bI * 128 + i;

    // ---------- prologue A: HCj[row][o] = h[row]@W1[32:64]; each wave does 16 rows ----------
    {
        v8s Aj0, Aj1;   // A = W1j^T : A[m=o][k] = W1[32+k][o]
        #pragma unroll
        for (int jj = 0; jj < 8; ++jj){
            Aj0[jj] = f2bf(EW1[(32 + q*8 + jj) * 32 + m16]);
            Aj1[jj] = f2bf(EW1[(32 + q*8 + jj) * 32 + 16 + m16]);
        }
        const int row = wid * 16 + m16;
        const float* hp = &Hin[(bI * 128 + row) * 32 + q * 8];
        const float4 h0 = *(const float4*)&hp[0];
        const float4 h1 = *(const float4*)&hp[4];
        v8s Bh;
        Bh[0]=f2bf(h0.x); Bh[1]=f2bf(h0.y); Bh[2]=f2bf(h0.z); Bh[3]=f2bf(h0.w);
        Bh[4]=f2bf(h1.x); Bh[5]=f2bf(h1.y); Bh[6]=f2bf(h1.z); Bh[7]=f2bf(h1.w);
        v4f d0 = {0.f,0.f,0.f,0.f}, d1 = {0.f,0.f,0.f,0.f};
        d0 = __builtin_amdgcn_mfma_f32_16x16x32_bf16(Aj0, Bh, d0, 0, 0, 0);
        d1 = __builtin_amdgcn_mfma_f32_16x16x32_bf16(Aj1, Bh, d1, 0, 0, 0);
        #pragma unroll
        for (int r = 0; r < 4; ++r){
            sm[L_HCJ + row * 36 + q*4 + r]      = d0[r];
            sm[L_HCJ + row * 36 + 16 + q*4 + r] = d1[r];
        }
    }
    // ---------- prologue B: hci (i-half + bias) for the block's 8 nodes ----------
    if (tid < 256){
        const int nl = tid >> 5, o = tid & 31;
        const float* hp = &Hin[(bI * 128 + grp * 8 + nl) * 32];
        float acc = EB1[o];
        #pragma unroll
        for (int k = 0; k < 32; ++k) acc = fmaf(hp[k], EW1[k * 32 + o], acc);
        sm[L_HCI + nl * 32 + o] = acc;
    }
    // ---------- prologue C: per-wave geometry, lane = edge ----------
    float* sgr = &sm[L_GR + wid * 384];   // stride-3 per edge
    float* sgd = &sm[L_GD + wid * 256];   // float2 per edge
    const float xi0 = X[bI*384 + i*3 + 0];
    const float xi1 = X[bI*384 + i*3 + 1];
    const float xi2 = X[bI*384 + i*3 + 2];
    #pragma unroll
    for (int p = 0; p < 2; ++p){
        const int slot = lane + 64 * p;
        const int js = (slot < NPE) ? slot : 126;
        const int j = js + ((js >= i) ? 1 : 0);
        const float* xj = &X[bI*384 + j*3];
        const float r0 = xi0 - xj[0], r1 = xi1 - xj[1], r2 = xi2 - xj[2];
        const float d2 = fmaf(r0, r0, fmaf(r1, r1, fmaf(r2, r2, 1e-6f)));
        const float d  = sqrtf(d2);
        const float rinv = fast_rcp(d + 1.0f);
        const float dsv = DS[bI*16256 + i*127 + js];
        sgr[slot*3 + 0] = r0 * rinv;
        sgr[slot*3 + 1] = r1 * rinv;
        sgr[slot*3 + 2] = r2 * rinv;
        *(float2*)&sgd[slot*2] = make_float2(d2, dsv * dsv);
    }
    __syncthreads();

    // ---------- persistent per-lane weight fragments ----------
    v8s Aw20, Aw21, Ac0, Ac1;
    #pragma unroll
    for (int jj = 0; jj < 8; ++jj){
        Aw20[jj] = f2bf(EW2[(q*8 + jj) * 32 + m16]);
        Aw21[jj] = f2bf(EW2[(q*8 + jj) * 32 + 16 + m16]);
        const int tau = (jj < 4) ? (q*4 + jj) : (16 + q*4 + (jj - 4));
        Ac0[jj] = f2bf(CW1[tau * 32 + m16]);
        Ac1[jj] = f2bf(CW1[tau * 32 + 16 + m16]);
    }
    f4u w64a, w64b, w65a, w65b, hcia, hcib, awa, awb, cwa, cwb;
    w64a.f4 = *(const float4*)&EW1[64*32 + q*8];
    w64b.f4 = *(const float4*)&EW1[64*32 + q*8 + 4];
    w65a.f4 = *(const float4*)&EW1[65*32 + q*8];
    w65b.f4 = *(const float4*)&EW1[65*32 + q*8 + 4];
    hcia.f4 = *(const float4*)&sm[L_HCI + wid*32 + q*8];
    hcib.f4 = *(const float4*)&sm[L_HCI + wid*32 + q*8 + 4];
    awa.f4  = *(const float4*)&AW[q*4];        // C-space: features q*4+r
    awb.f4  = *(const float4*)&AW[16 + q*4];
    cwa.f4  = *(const float4*)&CW2[q*4];
    cwb.f4  = *(const float4*)&CW2[16 + q*4];
    const float4 b2A = *(const float4*)&EB2[q*4];
    const float4 b2B = *(const float4*)&EB2[16 + q*4];
    const float4 cbA = *(const float4*)&CB1[q*4];
    const float4 cbB = *(const float4*)&CB1[16 + q*4];
    const float ab0 = AB[0];

    v2f ms2[4];
    #pragma unroll
    for (int g = 0; g < 4; ++g) ms2[g] = splat2(0.f);
    float xc0 = 0.f, xc1 = 0.f, xc2 = 0.f;

    // ---------- edge loop: 8 tiles x 16 edges ----------
    #pragma unroll 1
    for (int tl = 0; tl < 8; ++tl){
        const int e = tl * 16 + m16;
        const float valid = (e < NPE) ? 1.f : 0.f;
        const int js = (e < NPE) ? e : 126;
        const int j = js + ((js >= i) ? 1 : 0);

        const float2 dd = *(const float2*)&sgd[e*2];
        f4u hjA, hjB;
        hjA.f4 = *(const float4*)&sm[L_HCJ + j*36 + q*8];
        hjB.f4 = *(const float4*)&sm[L_HCJ + j*36 + q*8 + 4];
        const v2f d2s  = splat2(dd.x);
        const v2f ds2s = splat2(dd.y);

        // t1 (B-frag slots k=q*8+jj), packed-f32 chains + shared-rcp silu
        v2f t01, t23, t45, t67;
        {
            v2f z01 = hcia.v2[0] + hjA.v2[0];
            z01 = __builtin_elementwise_fma(d2s, w64a.v2[0], z01);
            z01 = __builtin_elementwise_fma(ds2s, w65a.v2[0], z01);
            v2f z23 = hcia.v2[1] + hjA.v2[1];
            z23 = __builtin_elementwise_fma(d2s, w64a.v2[1], z23);
            z23 = __builtin_elementwise_fma(ds2s, w65a.v2[1], z23);
            silu4(z01, z23, t01, t23);
            v2f z45 = hcib.v2[0] + hjB.v2[0];
            z45 = __builtin_elementwise_fma(d2s, w64b.v2[0], z45);
            z45 = __builtin_elementwise_fma(ds2s, w65b.v2[0], z45);
            v2f z67 = hcib.v2[1] + hjB.v2[1];
            z67 = __builtin_elementwise_fma(d2s, w64b.v2[1], z67);
            z67 = __builtin_elementwise_fma(ds2s, w65b.v2[1], z67);
            silu4(z45, z67, t45, t67);
        }
        v8s Bt;
        Bt[0]=f2bf(t01.x); Bt[1]=f2bf(t01.y); Bt[2]=f2bf(t23.x); Bt[3]=f2bf(t23.y);
        Bt[4]=f2bf(t45.x); Bt[5]=f2bf(t45.y); Bt[6]=f2bf(t67.x); Bt[7]=f2bf(t67.y);

        // layer 2: D[f][e]
        v4f c0 = {b2A.x, b2A.y, b2A.z, b2A.w};
        v4f c1 = {b2B.x, b2B.y, b2B.z, b2B.w};
        c0 = __builtin_amdgcn_mfma_f32_16x16x32_bf16(Aw20, Bt, c0, 0, 0, 0);
        c1 = __builtin_amdgcn_mfma_f32_16x16x32_bf16(Aw21, Bt, c1, 0, 0, 0);
        v2f sa, sb, sc, sd;
        {
            v2f za, zb;
            za.x=c0[0]; za.y=c0[1]; zb.x=c0[2]; zb.y=c0[3];
            silu4(za, zb, sa, sb);
            za.x=c1[0]; za.y=c1[1]; zb.x=c1[2]; zb.y=c1[3];
            silu4(za, zb, sc, sd);
        }

        // attention gate (C-space ordering)
        v2f lgv = sa * awa.v2[0];
        lgv = __builtin_elementwise_fma(sb, awa.v2[1], lgv);
        lgv = __builtin_elementwise_fma(sc, awb.v2[0], lgv);
        lgv = __builtin_elementwise_fma(sd, awb.v2[1], lgv);
        float lg = lgv.x + lgv.y;
        lg += __shfl_xor(lg, 16, 64);
        lg += __shfl_xor(lg, 32, 64);
        const float att = sigmoidf_(lg + ab0) * valid;
        const v2f atts = splat2(att);

        const v2f g0 = sa * atts, g1 = sb * atts, g2 = sc * atts, g3 = sd * atts;
        ms2[0] += g0; ms2[1] += g1; ms2[2] += g2; ms2[3] += g3;
        v8s Bm;
        Bm[0]=f2bf(g0.x); Bm[1]=f2bf(g0.y); Bm[2]=f2bf(g1.x); Bm[3]=f2bf(g1.y);
        Bm[4]=f2bf(g2.x); Bm[5]=f2bf(g2.y); Bm[6]=f2bf(g3.x); Bm[7]=f2bf(g3.y);

        // coord head
        v4f e0 = {cbA.x, cbA.y, cbA.z, cbA.w};
        v4f e1 = {cbB.x, cbB.y, cbB.z, cbB.w};
        e0 = __builtin_amdgcn_mfma_f32_16x16x32_bf16(Ac0, Bm, e0, 0, 0, 0);
        e1 = __builtin_amdgcn_mfma_f32_16x16x32_bf16(Ac1, Bm, e1, 0, 0, 0);
        v2f ca, cb, cc, cd;
        {
            v2f za, zb;
            za.x=e0[0]; za.y=e0[1]; zb.x=e0[2]; zb.y=e0[3];
            silu4(za, zb, ca, cb);
            za.x=e1[0]; za.y=e1[1]; zb.x=e1[2]; zb.y=e1[3];
            silu4(za, zb, cc, cd);
        }
        v2f trv = ca * cwa.v2[0];
        trv = __builtin_elementwise_fma(cb, cwa.v2[1], trv);
        trv = __builtin_elementwise_fma(cc, cwb.v2[0], trv);
        trv = __builtin_elementwise_fma(cd, cwb.v2[1], trv);
        float tr = trv.x + trv.y;
        tr += __shfl_xor(tr, 16, 64);
        tr += __shfl_xor(tr, 32, 64);

        // r pre-scaled by rinv in prologue; just mask and accumulate
        const float coef = tanhf_fast(tr) * valid;
        const float rs0 = sgr[e*3 + 0];
        const float rs1 = sgr[e*3 + 1];
        const float rs2 = sgr[e*3 + 2];
        xc0 = fmaf(rs0, coef, xc0);
        xc1 = fmaf(rs1, coef, xc1);
        xc2 = fmaf(rs2, coef, xc2);
    }

    // ---------- reduce ms over the 16 edge-lanes within each quad ----------
    float msv[8] = {ms2[0].x, ms2[0].y, ms2[1].x, ms2[1].y,
                    ms2[2].x, ms2[2].y, ms2[3].x, ms2[3].y};
    #pragma unroll
    for (int jj = 0; jj < 8; ++jj){
        float v = msv[jj];
        v += __shfl_xor(v, 1, 64); v += __shfl_xor(v, 2, 64);
        v += __shfl_xor(v, 4, 64); v += __shfl_xor(v, 8, 64);
        msv[jj] = v;
    }
    // ---------- reduce xc over all 64 lanes (each edge counted 4x) ----------
    {
        float v0 = xc0, v1 = xc1, v2 = xc2;
        #pragma unroll
        for (int s = 1; s < 64; s <<= 1){
            v0 += __shfl_xor(v0, s, 64);
            v1 += __shfl_xor(v1, s, 64);
            v2 += __shfl_xor(v2, s, 64);
        }
        xc0 = v0 * 0.25f; xc1 = v1 * 0.25f; xc2 = v2 * 0.25f;
    }

    if (lane < 3){
        const float xiv = (lane == 0) ? xi0 : ((lane == 1) ? xi1 : xi2);
        const float xcv = (lane == 0) ? xc0 : ((lane == 1) ? xc1 : xc2);
        OUT[bI*384 + i*3 + lane] = fmaf(xcv, 5.0f, xiv);
    }

    // ---------- stash ms (feature-ordered) into now-free geometry LDS ----------
    if (m16 == 0){
        #pragma unroll
        for (int jj = 0; jj < 8; ++jj){
            const int tau = (jj < 4) ? (q*4 + jj) : (16 + q*4 + (jj - 4));
            sgr[tau] = msv[jj];
        }
    }

    // ---------- node MLP ----------
    const int o = lane & 31;
    const float* hp = &Hin[node * 32];
    float a1 = NB1[o];
    #pragma unroll
    for (int k = 0; k < 32; ++k) a1 = fmaf(hp[k], NW1[k * 32 + o], a1);
    #pragma unroll
    for (int k = 0; k < 32; ++k) a1 = fmaf(sgr[k], NW1[(32 + k) * 32 + o], a1);
    const float s1v = a1 * sigmoidf_(a1);
    float a2 = NB2[o];
    #pragma unroll
    for (int k = 0; k < 32; ++k) a2 = fmaf(__shfl(s1v, k, 64), NW2[k * 32 + o], a2);
    if (lane < 32)
        OUT[49152 + node * 32 + o] = hp[o] + a2;
}

extern "C" void kernel_launch(void* const* d_in, const int* in_sizes, int n_in,
                              void* d_out, int out_size, void* d_ws, size_t ws_size,
                              hipStream_t stream) {
    (void)in_sizes; (void)n_in; (void)out_size; (void)d_ws; (void)ws_size;
    eq_gnn_fused<<<dim3(2048), dim3(512), 0, stream>>>(
        (const float*)d_in[0],  (const float*)d_in[1],  (const float*)d_in[2],
        (const float*)d_in[3],  (const float*)d_in[4],  (const float*)d_in[5],  (const float*)d_in[6],
        (const float*)d_in[7],  (const float*)d_in[8],  (const float*)d_in[9],  (const float*)d_in[10],
        (const float*)d_in[11], (const float*)d_in[12], (const float*)d_in[13],
        (const float*)d_in[14], (const float*)d_in[15],
        (float*)d_out);
}

// Round 8
// 158.957 us; speedup vs baseline: 1.0725x; 1.0328x over previous
//
#include <hip/hip_runtime.h>
#include <hip/hip_bf16.h>

#define NPE 127

typedef short v8s __attribute__((ext_vector_type(8)));
typedef float v4f __attribute__((ext_vector_type(4)));
typedef float v2f __attribute__((ext_vector_type(2)));

// LDS float offsets (512-thread block = 8 waves = 8 nodes; HCJ shared per batch)
// History: R2 82.3us = best (39936B LDS, no hints, VGPR 64, occ 36% = 3 waves/SIMD).
// R1 (512,8): spill disaster. R3 (512,4): neutral. R4 LDS weight table: -15%.
// R6 2-tile ILP: reg boundary crossed -> 2 waves/SIMD, -8%. R7 silu4 shared-rcp:
// -6% (trans not binding; VALU count + chain length is). Conclusion: VALU-issue
// bound; only instruction removal helps.
// R8: replace __float2bfloat16 pairs in the edge loop with v_cvt_pk_bf16_f32
// (gfx950 has no scalar bf16 cvt; scalar path is likely a 4-instr integer RNE
// sequence). 16 f2bf/tile -> 8 cvt_pk/tile. Single-variable change on R2 base.
#define L_HCJ 0       // 128 rows x 36
#define L_HCI 4608    // 8 nodes x 32
#define L_GR  4864    // 8 waves x 128 x 3 {r0*rinv, r1*rinv, r2*rinv}
#define L_GD  7936    // 8 waves x 128 x float2 {d2, ds2}
#define L_TOT 9984    // 39936 B -> 4 blocks/CU by LDS

__device__ __forceinline__ float fast_rcp(float x){ return __builtin_amdgcn_rcpf(x); }
__device__ __forceinline__ float exp2_fast(float x){
#if __has_builtin(__builtin_amdgcn_exp2f)
    return __builtin_amdgcn_exp2f(x);
#else
    return exp2f(x);
#endif
}
#define LOG2E 1.44269504f
__device__ __forceinline__ float sigmoidf_(float x){
    return fast_rcp(1.0f + exp2_fast(-LOG2E * x));
}
__device__ __forceinline__ float tanhf_fast(float x){
    return fmaf(-2.0f, fast_rcp(1.0f + exp2_fast(2.0f * LOG2E * x)), 1.0f);
}
__device__ __forceinline__ v2f splat2(float v){ v2f r; r.x = v; r.y = v; return r; }
// packed-f32 silu: fma/add/mul lower to v_pk_*; exp/rcp stay scalar (per-element)
__device__ __forceinline__ v2f silu2(v2f x){
    v2f t = x * splat2(-LOG2E);
    v2f e; e.x = exp2_fast(t.x); e.y = exp2_fast(t.y);
    v2f d = e + splat2(1.0f);
    v2f r; r.x = fast_rcp(d.x); r.y = fast_rcp(d.y);
    return x * r;
}
__device__ __forceinline__ short f2bf(float x){
    __hip_bfloat16 h = __float2bfloat16(x);
    return *reinterpret_cast<short*>(&h);
}
// Packed f32->bf16 pair: dword = {lo=bf16(a), hi=bf16(b)}. gfx950 has no
// scalar bf16 cvt; this is 1 instr vs ~4/elem for the integer RNE fallback.
// Register-only asm: ordering enforced by dataflow into the consuming MFMA.
__device__ __forceinline__ unsigned cvt_pk_bf16(float a, float b){
    unsigned r;
    asm("v_cvt_pk_bf16_f32 %0, %1, %2" : "=v"(r) : "v"(a), "v"(b));
    return r;
}
union bfrag { v8s s8; unsigned u[4]; };
union f4u { float4 f4; v2f v2[2]; float f[4]; };

__global__ __launch_bounds__(512)
void eq_gnn_fused(const float* __restrict__ X, const float* __restrict__ Hin,
                  const float* __restrict__ DS,
                  const float* __restrict__ EW1, const float* __restrict__ EB1,
                  const float* __restrict__ EW2, const float* __restrict__ EB2,
                  const float* __restrict__ NW1, const float* __restrict__ NB1,
                  const float* __restrict__ NW2, const float* __restrict__ NB2,
                  const float* __restrict__ CW1, const float* __restrict__ CB1,
                  const float* __restrict__ CW2,
                  const float* __restrict__ AW,  const float* __restrict__ AB,
                  float* __restrict__ OUT)
{
    __shared__ float sm[L_TOT];
    const int tid  = threadIdx.x;
    const int lane = tid & 63;
    const int wid  = tid >> 6;           // 0..7
    const int m16  = lane & 15;
    const int q    = lane >> 4;
    const int bI   = blockIdx.x >> 4;    // batch
    const int grp  = blockIdx.x & 15;
    const int i    = grp * 8 + wid;      // this wave's node
    const int node = bI * 128 + i;

    // ---------- prologue A: HCj[row][o] = h[row]@W1[32:64]; each wave does 16 rows ----------
    {
        v8s Aj0, Aj1;   // A = W1j^T : A[m=o][k] = W1[32+k][o]
        #pragma unroll
        for (int jj = 0; jj < 8; ++jj){
            Aj0[jj] = f2bf(EW1[(32 + q*8 + jj) * 32 + m16]);
            Aj1[jj] = f2bf(EW1[(32 + q*8 + jj) * 32 + 16 + m16]);
        }
        const int row = wid * 16 + m16;
        const float* hp = &Hin[(bI * 128 + row) * 32 + q * 8];
        const float4 h0 = *(const float4*)&hp[0];
        const float4 h1 = *(const float4*)&hp[4];
        bfrag Bh;
        Bh.u[0] = cvt_pk_bf16(h0.x, h0.y);
        Bh.u[1] = cvt_pk_bf16(h0.z, h0.w);
        Bh.u[2] = cvt_pk_bf16(h1.x, h1.y);
        Bh.u[3] = cvt_pk_bf16(h1.z, h1.w);
        v4f d0 = {0.f,0.f,0.f,0.f}, d1 = {0.f,0.f,0.f,0.f};
        d0 = __builtin_amdgcn_mfma_f32_16x16x32_bf16(Aj0, Bh.s8, d0, 0, 0, 0);
        d1 = __builtin_amdgcn_mfma_f32_16x16x32_bf16(Aj1, Bh.s8, d1, 0, 0, 0);
        #pragma unroll
        for (int r = 0; r < 4; ++r){
            sm[L_HCJ + row * 36 + q*4 + r]      = d0[r];
            sm[L_HCJ + row * 36 + 16 + q*4 + r] = d1[r];
        }
    }
    // ---------- prologue B: hci (i-half + bias) for the block's 8 nodes ----------
    if (tid < 256){
        const int nl = tid >> 5, o = tid & 31;
        const float* hp = &Hin[(bI * 128 + grp * 8 + nl) * 32];
        float acc = EB1[o];
        #pragma unroll
        for (int k = 0; k < 32; ++k) acc = fmaf(hp[k], EW1[k * 32 + o], acc);
        sm[L_HCI + nl * 32 + o] = acc;
    }
    // ---------- prologue C: per-wave geometry, lane = edge ----------
    float* sgr = &sm[L_GR + wid * 384];   // stride-3 per edge
    float* sgd = &sm[L_GD + wid * 256];   // float2 per edge
    const float xi0 = X[bI*384 + i*3 + 0];
    const float xi1 = X[bI*384 + i*3 + 1];
    const float xi2 = X[bI*384 + i*3 + 2];
    #pragma unroll
    for (int p = 0; p < 2; ++p){
        const int slot = lane + 64 * p;
        const int js = (slot < NPE) ? slot : 126;
        const int j = js + ((js >= i) ? 1 : 0);
        const float* xj = &X[bI*384 + j*3];
        const float r0 = xi0 - xj[0], r1 = xi1 - xj[1], r2 = xi2 - xj[2];
        const float d2 = fmaf(r0, r0, fmaf(r1, r1, fmaf(r2, r2, 1e-6f)));
        const float d  = sqrtf(d2);
        const float rinv = fast_rcp(d + 1.0f);
        const float dsv = DS[bI*16256 + i*127 + js];
        sgr[slot*3 + 0] = r0 * rinv;
        sgr[slot*3 + 1] = r1 * rinv;
        sgr[slot*3 + 2] = r2 * rinv;
        *(float2*)&sgd[slot*2] = make_float2(d2, dsv * dsv);
    }
    __syncthreads();

    // ---------- persistent per-lane weight fragments ----------
    v8s Aw20, Aw21, Ac0, Ac1;
    #pragma unroll
    for (int jj = 0; jj < 8; ++jj){
        Aw20[jj] = f2bf(EW2[(q*8 + jj) * 32 + m16]);
        Aw21[jj] = f2bf(EW2[(q*8 + jj) * 32 + 16 + m16]);
        const int tau = (jj < 4) ? (q*4 + jj) : (16 + q*4 + (jj - 4));
        Ac0[jj] = f2bf(CW1[tau * 32 + m16]);
        Ac1[jj] = f2bf(CW1[tau * 32 + 16 + m16]);
    }
    f4u w64a, w64b, w65a, w65b, hcia, hcib, awa, awb, cwa, cwb;
    w64a.f4 = *(const float4*)&EW1[64*32 + q*8];
    w64b.f4 = *(const float4*)&EW1[64*32 + q*8 + 4];
    w65a.f4 = *(const float4*)&EW1[65*32 + q*8];
    w65b.f4 = *(const float4*)&EW1[65*32 + q*8 + 4];
    hcia.f4 = *(const float4*)&sm[L_HCI + wid*32 + q*8];
    hcib.f4 = *(const float4*)&sm[L_HCI + wid*32 + q*8 + 4];
    awa.f4  = *(const float4*)&AW[q*4];        // C-space: features q*4+r
    awb.f4  = *(const float4*)&AW[16 + q*4];
    cwa.f4  = *(const float4*)&CW2[q*4];
    cwb.f4  = *(const float4*)&CW2[16 + q*4];
    const float4 b2A = *(const float4*)&EB2[q*4];
    const float4 b2B = *(const float4*)&EB2[16 + q*4];
    const float4 cbA = *(const float4*)&CB1[q*4];
    const float4 cbB = *(const float4*)&CB1[16 + q*4];
    const float ab0 = AB[0];

    v2f ms2[4];
    #pragma unroll
    for (int g = 0; g < 4; ++g) ms2[g] = splat2(0.f);
    float xc0 = 0.f, xc1 = 0.f, xc2 = 0.f;

    // ---------- edge loop: 8 tiles x 16 edges ----------
    #pragma unroll 1
    for (int tl = 0; tl < 8; ++tl){
        const int e = tl * 16 + m16;
        const float valid = (e < NPE) ? 1.f : 0.f;
        const int js = (e < NPE) ? e : 126;
        const int j = js + ((js >= i) ? 1 : 0);

        const float2 dd = *(const float2*)&sgd[e*2];
        f4u hjA, hjB;
        hjA.f4 = *(const float4*)&sm[L_HCJ + j*36 + q*8];
        hjB.f4 = *(const float4*)&sm[L_HCJ + j*36 + q*8 + 4];
        const v2f d2s  = splat2(dd.x);
        const v2f ds2s = splat2(dd.y);

        // t1 (B-frag slots k=q*8+jj), packed-f32 chains
        v2f t01, t23, t45, t67;
        {
            v2f z;
            z = hcia.v2[0] + hjA.v2[0];
            z = __builtin_elementwise_fma(d2s, w64a.v2[0], z);
            z = __builtin_elementwise_fma(ds2s, w65a.v2[0], z);
            t01 = silu2(z);
            z = hcia.v2[1] + hjA.v2[1];
            z = __builtin_elementwise_fma(d2s, w64a.v2[1], z);
            z = __builtin_elementwise_fma(ds2s, w65a.v2[1], z);
            t23 = silu2(z);
            z = hcib.v2[0] + hjB.v2[0];
            z = __builtin_elementwise_fma(d2s, w64b.v2[0], z);
            z = __builtin_elementwise_fma(ds2s, w65b.v2[0], z);
            t45 = silu2(z);
            z = hcib.v2[1] + hjB.v2[1];
            z = __builtin_elementwise_fma(d2s, w64b.v2[1], z);
            z = __builtin_elementwise_fma(ds2s, w65b.v2[1], z);
            t67 = silu2(z);
        }
        bfrag Bt;
        Bt.u[0] = cvt_pk_bf16(t01.x, t01.y);
        Bt.u[1] = cvt_pk_bf16(t23.x, t23.y);
        Bt.u[2] = cvt_pk_bf16(t45.x, t45.y);
        Bt.u[3] = cvt_pk_bf16(t67.x, t67.y);

        // layer 2: D[f][e]
        v4f c0 = {b2A.x, b2A.y, b2A.z, b2A.w};
        v4f c1 = {b2B.x, b2B.y, b2B.z, b2B.w};
        c0 = __builtin_amdgcn_mfma_f32_16x16x32_bf16(Aw20, Bt.s8, c0, 0, 0, 0);
        c1 = __builtin_amdgcn_mfma_f32_16x16x32_bf16(Aw21, Bt.s8, c1, 0, 0, 0);
        v2f sa, sb, sc, sd;
        { v2f z; z.x=c0[0]; z.y=c0[1]; sa = silu2(z); }
        { v2f z; z.x=c0[2]; z.y=c0[3]; sb = silu2(z); }
        { v2f z; z.x=c1[0]; z.y=c1[1]; sc = silu2(z); }
        { v2f z; z.x=c1[2]; z.y=c1[3]; sd = silu2(z); }

        // attention gate (C-space ordering)
        v2f lgv = sa * awa.v2[0];
        lgv = __builtin_elementwise_fma(sb, awa.v2[1], lgv);
        lgv = __builtin_elementwise_fma(sc, awb.v2[0], lgv);
        lgv = __builtin_elementwise_fma(sd, awb.v2[1], lgv);
        float lg = lgv.x + lgv.y;
        lg += __shfl_xor(lg, 16, 64);
        lg += __shfl_xor(lg, 32, 64);
        const float att = sigmoidf_(lg + ab0) * valid;
        const v2f atts = splat2(att);

        const v2f g0 = sa * atts, g1 = sb * atts, g2 = sc * atts, g3 = sd * atts;
        ms2[0] += g0; ms2[1] += g1; ms2[2] += g2; ms2[3] += g3;
        bfrag Bm;
        Bm.u[0] = cvt_pk_bf16(g0.x, g0.y);
        Bm.u[1] = cvt_pk_bf16(g1.x, g1.y);
        Bm.u[2] = cvt_pk_bf16(g2.x, g2.y);
        Bm.u[3] = cvt_pk_bf16(g3.x, g3.y);

        // coord head
        v4f e0 = {cbA.x, cbA.y, cbA.z, cbA.w};
        v4f e1 = {cbB.x, cbB.y, cbB.z, cbB.w};
        e0 = __builtin_amdgcn_mfma_f32_16x16x32_bf16(Ac0, Bm.s8, e0, 0, 0, 0);
        e1 = __builtin_amdgcn_mfma_f32_16x16x32_bf16(Ac1, Bm.s8, e1, 0, 0, 0);
        v2f ca, cb, cc, cd;
        { v2f z; z.x=e0[0]; z.y=e0[1]; ca = silu2(z); }
        { v2f z; z.x=e0[2]; z.y=e0[3]; cb = silu2(z); }
        { v2f z; z.x=e1[0]; z.y=e1[1]; cc = silu2(z); }
        { v2f z; z.x=e1[2]; z.y=e1[3]; cd = silu2(z); }
        v2f trv = ca * cwa.v2[0];
        trv = __builtin_elementwise_fma(cb, cwa.v2[1], trv);
        trv = __builtin_elementwise_fma(cc, cwb.v2[0], trv);
        trv = __builtin_elementwise_fma(cd, cwb.v2[1], trv);
        float tr = trv.x + trv.y;
        tr += __shfl_xor(tr, 16, 64);
        tr += __shfl_xor(tr, 32, 64);

        // r pre-scaled by rinv in prologue; just mask and accumulate
        const float coef = tanhf_fast(tr) * valid;
        const float rs0 = sgr[e*3 + 0];
        const float rs1 = sgr[e*3 + 1];
        const float rs2 = sgr[e*3 + 2];
        xc0 = fmaf(rs0, coef, xc0);
        xc1 = fmaf(rs1, coef, xc1);
        xc2 = fmaf(rs2, coef, xc2);
    }

    // ---------- reduce ms over the 16 edge-lanes within each quad ----------
    float msv[8] = {ms2[0].x, ms2[0].y, ms2[1].x, ms2[1].y,
                    ms2[2].x, ms2[2].y, ms2[3].x, ms2[3].y};
    #pragma unroll
    for (int jj = 0; jj < 8; ++jj){
        float v = msv[jj];
        v += __shfl_xor(v, 1, 64); v += __shfl_xor(v, 2, 64);
        v += __shfl_xor(v, 4, 64); v += __shfl_xor(v, 8, 64);
        msv[jj] = v;
    }
    // ---------- reduce xc over all 64 lanes (each edge counted 4x) ----------
    {
        float v0 = xc0, v1 = xc1, v2 = xc2;
        #pragma unroll
        for (int s = 1; s < 64; s <<= 1){
            v0 += __shfl_xor(v0, s, 64);
            v1 += __shfl_xor(v1, s, 64);
            v2 += __shfl_xor(v2, s, 64);
        }
        xc0 = v0 * 0.25f; xc1 = v1 * 0.25f; xc2 = v2 * 0.25f;
    }

    if (lane < 3){
        const float xiv = (lane == 0) ? xi0 : ((lane == 1) ? xi1 : xi2);
        const float xcv = (lane == 0) ? xc0 : ((lane == 1) ? xc1 : xc2);
        OUT[bI*384 + i*3 + lane] = fmaf(xcv, 5.0f, xiv);
    }

    // ---------- stash ms (feature-ordered) into now-free geometry LDS ----------
    if (m16 == 0){
        #pragma unroll
        for (int jj = 0; jj < 8; ++jj){
            const int tau = (jj < 4) ? (q*4 + jj) : (16 + q*4 + (jj - 4));
            sgr[tau] = msv[jj];
        }
    }

    // ---------- node MLP ----------
    const int o = lane & 31;
    const float* hp = &Hin[node * 32];
    float a1 = NB1[o];
    #pragma unroll
    for (int k = 0; k < 32; ++k) a1 = fmaf(hp[k], NW1[k * 32 + o], a1);
    #pragma unroll
    for (int k = 0; k < 32; ++k) a1 = fmaf(sgr[k], NW1[(32 + k) * 32 + o], a1);
    const float s1v = a1 * sigmoidf_(a1);
    float a2 = NB2[o];
    #pragma unroll
    for (int k = 0; k < 32; ++k) a2 = fmaf(__shfl(s1v, k, 64), NW2[k * 32 + o], a2);
    if (lane < 32)
        OUT[49152 + node * 32 + o] = hp[o] + a2;
}

extern "C" void kernel_launch(void* const* d_in, const int* in_sizes, int n_in,
                              void* d_out, int out_size, void* d_ws, size_t ws_size,
                              hipStream_t stream) {
    (void)in_sizes; (void)n_in; (void)out_size; (void)d_ws; (void)ws_size;
    eq_gnn_fused<<<dim3(2048), dim3(512), 0, stream>>>(
        (const float*)d_in[0],  (const float*)d_in[1],  (const float*)d_in[2],
        (const float*)d_in[3],  (const float*)d_in[4],  (const float*)d_in[5],  (const float*)d_in[6],
        (const float*)d_in[7],  (const float*)d_in[8],  (const float*)d_in[9],  (const float*)d_in[10],
        (const float*)d_in[11], (const float*)d_in[12], (const float*)d_in[13],
        (const float*)d_in[14], (const float*)d_in[15],
        (float*)d_out);
}

// Round 9
// 158.476 us; speedup vs baseline: 1.0758x; 1.0030x over previous
//
#include <hip/hip_runtime.h>
#include <hip/hip_bf16.h>

#define NPE 127

typedef short v8s __attribute__((ext_vector_type(8)));
typedef float v4f __attribute__((ext_vector_type(4)));
typedef float v2f __attribute__((ext_vector_type(2)));

// LDS float offsets (512-thread block = 8 waves = 8 nodes; HCJ shared per batch)
// History: R2 82.3us = best (39936B LDS, no hints, VGPR 64, occ ~36% = 3 waves/SIMD,
//   ~100-reg hidden AGPR segment blocks 4th wave). R1 (512,8): spill disaster.
//   R3 (512,4): neutral. R4 LDS weight table: -15%. R6 2-tile ILP: crossed reg
//   boundary -> -8%. R7 silu4 shared-rcp: -6% (chain length dominates).
//   R8 hand cvt_pk: -3% (compiler's scalar cast already fine; m240 confirmed).
// R9: kernel is latency-bound on per-tile serial chains; the gate/tr reductions
//   put 4 DS-shfl round-trips (~30-50cy each + lgkm wait) on the critical path.
//   Replace the xor-32 hop with v_permlane32_swap_b32 (pure VALU, gfx950-new,
//   1.2x vs ds_bpermute per m255): mov+swap+add, no DS, no reg delta, identical
//   arithmetic. xor-16 hop stays DS (permlane16_swap unverified).
#define L_HCJ 0       // 128 rows x 36
#define L_HCI 4608    // 8 nodes x 32
#define L_GR  4864    // 8 waves x 128 x 3 {r0*rinv, r1*rinv, r2*rinv}
#define L_GD  7936    // 8 waves x 128 x float2 {d2, ds2}
#define L_TOT 9984    // 39936 B -> 4 blocks/CU by LDS

__device__ __forceinline__ float fast_rcp(float x){ return __builtin_amdgcn_rcpf(x); }
__device__ __forceinline__ float exp2_fast(float x){
#if __has_builtin(__builtin_amdgcn_exp2f)
    return __builtin_amdgcn_exp2f(x);
#else
    return exp2f(x);
#endif
}
#define LOG2E 1.44269504f
__device__ __forceinline__ float sigmoidf_(float x){
    return fast_rcp(1.0f + exp2_fast(-LOG2E * x));
}
__device__ __forceinline__ float tanhf_fast(float x){
    return fmaf(-2.0f, fast_rcp(1.0f + exp2_fast(2.0f * LOG2E * x)), 1.0f);
}
__device__ __forceinline__ v2f splat2(float v){ v2f r; r.x = v; r.y = v; return r; }
// packed-f32 silu: fma/add/mul lower to v_pk_*; exp/rcp stay scalar (per-element)
__device__ __forceinline__ v2f silu2(v2f x){
    v2f t = x * splat2(-LOG2E);
    v2f e; e.x = exp2_fast(t.x); e.y = exp2_fast(t.y);
    v2f d = e + splat2(1.0f);
    v2f r; r.x = fast_rcp(d.x); r.y = fast_rcp(d.y);
    return x * r;
}
__device__ __forceinline__ short f2bf(float x){
    __hip_bfloat16 h = __float2bfloat16(x);
    return *reinterpret_cast<short*>(&h);
}
// x + x[lane^32] for all lanes, pure VALU (no DS round-trip).
// v_permlane32_swap_b32 a,b : a.hi <-> b.lo. With a=b=x:
//   a = {x.lo, x.lo}, b = {x.hi, x.hi}  ->  a+b = x + x^32 on every lane.
__device__ __forceinline__ float xor32_add(float x){
    float a = x, b = x;
    asm("v_permlane32_swap_b32 %0, %1" : "+v"(a), "+v"(b));
    return a + b;
}
union f4u { float4 f4; v2f v2[2]; float f[4]; };

__global__ __launch_bounds__(512)
void eq_gnn_fused(const float* __restrict__ X, const float* __restrict__ Hin,
                  const float* __restrict__ DS,
                  const float* __restrict__ EW1, const float* __restrict__ EB1,
                  const float* __restrict__ EW2, const float* __restrict__ EB2,
                  const float* __restrict__ NW1, const float* __restrict__ NB1,
                  const float* __restrict__ NW2, const float* __restrict__ NB2,
                  const float* __restrict__ CW1, const float* __restrict__ CB1,
                  const float* __restrict__ CW2,
                  const float* __restrict__ AW,  const float* __restrict__ AB,
                  float* __restrict__ OUT)
{
    __shared__ float sm[L_TOT];
    const int tid  = threadIdx.x;
    const int lane = tid & 63;
    const int wid  = tid >> 6;           // 0..7
    const int m16  = lane & 15;
    const int q    = lane >> 4;
    const int bI   = blockIdx.x >> 4;    // batch
    const int grp  = blockIdx.x & 15;
    const int i    = grp * 8 + wid;      // this wave's node
    const int node = bI * 128 + i;

    // ---------- prologue A: HCj[row][o] = h[row]@W1[32:64]; each wave does 16 rows ----------
    {
        v8s Aj0, Aj1;   // A = W1j^T : A[m=o][k] = W1[32+k][o]
        #pragma unroll
        for (int jj = 0; jj < 8; ++jj){
            Aj0[jj] = f2bf(EW1[(32 + q*8 + jj) * 32 + m16]);
            Aj1[jj] = f2bf(EW1[(32 + q*8 + jj) * 32 + 16 + m16]);
        }
        const int row = wid * 16 + m16;
        const float* hp = &Hin[(bI * 128 + row) * 32 + q * 8];
        const float4 h0 = *(const float4*)&hp[0];
        const float4 h1 = *(const float4*)&hp[4];
        v8s Bh;
        Bh[0]=f2bf(h0.x); Bh[1]=f2bf(h0.y); Bh[2]=f2bf(h0.z); Bh[3]=f2bf(h0.w);
        Bh[4]=f2bf(h1.x); Bh[5]=f2bf(h1.y); Bh[6]=f2bf(h1.z); Bh[7]=f2bf(h1.w);
        v4f d0 = {0.f,0.f,0.f,0.f}, d1 = {0.f,0.f,0.f,0.f};
        d0 = __builtin_amdgcn_mfma_f32_16x16x32_bf16(Aj0, Bh, d0, 0, 0, 0);
        d1 = __builtin_amdgcn_mfma_f32_16x16x32_bf16(Aj1, Bh, d1, 0, 0, 0);
        #pragma unroll
        for (int r = 0; r < 4; ++r){
            sm[L_HCJ + row * 36 + q*4 + r]      = d0[r];
            sm[L_HCJ + row * 36 + 16 + q*4 + r] = d1[r];
        }
    }
    // ---------- prologue B: hci (i-half + bias) for the block's 8 nodes ----------
    if (tid < 256){
        const int nl = tid >> 5, o = tid & 31;
        const float* hp = &Hin[(bI * 128 + grp * 8 + nl) * 32];
        float acc = EB1[o];
        #pragma unroll
        for (int k = 0; k < 32; ++k) acc = fmaf(hp[k], EW1[k * 32 + o], acc);
        sm[L_HCI + nl * 32 + o] = acc;
    }
    // ---------- prologue C: per-wave geometry, lane = edge ----------
    float* sgr = &sm[L_GR + wid * 384];   // stride-3 per edge
    float* sgd = &sm[L_GD + wid * 256];   // float2 per edge
    const float xi0 = X[bI*384 + i*3 + 0];
    const float xi1 = X[bI*384 + i*3 + 1];
    const float xi2 = X[bI*384 + i*3 + 2];
    #pragma unroll
    for (int p = 0; p < 2; ++p){
        const int slot = lane + 64 * p;
        const int js = (slot < NPE) ? slot : 126;
        const int j = js + ((js >= i) ? 1 : 0);
        const float* xj = &X[bI*384 + j*3];
        const float r0 = xi0 - xj[0], r1 = xi1 - xj[1], r2 = xi2 - xj[2];
        const float d2 = fmaf(r0, r0, fmaf(r1, r1, fmaf(r2, r2, 1e-6f)));
        const float d  = sqrtf(d2);
        const float rinv = fast_rcp(d + 1.0f);
        const float dsv = DS[bI*16256 + i*127 + js];
        sgr[slot*3 + 0] = r0 * rinv;
        sgr[slot*3 + 1] = r1 * rinv;
        sgr[slot*3 + 2] = r2 * rinv;
        *(float2*)&sgd[slot*2] = make_float2(d2, dsv * dsv);
    }
    __syncthreads();

    // ---------- persistent per-lane weight fragments ----------
    v8s Aw20, Aw21, Ac0, Ac1;
    #pragma unroll
    for (int jj = 0; jj < 8; ++jj){
        Aw20[jj] = f2bf(EW2[(q*8 + jj) * 32 + m16]);
        Aw21[jj] = f2bf(EW2[(q*8 + jj) * 32 + 16 + m16]);
        const int tau = (jj < 4) ? (q*4 + jj) : (16 + q*4 + (jj - 4));
        Ac0[jj] = f2bf(CW1[tau * 32 + m16]);
        Ac1[jj] = f2bf(CW1[tau * 32 + 16 + m16]);
    }
    f4u w64a, w64b, w65a, w65b, hcia, hcib, awa, awb, cwa, cwb;
    w64a.f4 = *(const float4*)&EW1[64*32 + q*8];
    w64b.f4 = *(const float4*)&EW1[64*32 + q*8 + 4];
    w65a.f4 = *(const float4*)&EW1[65*32 + q*8];
    w65b.f4 = *(const float4*)&EW1[65*32 + q*8 + 4];
    hcia.f4 = *(const float4*)&sm[L_HCI + wid*32 + q*8];
    hcib.f4 = *(const float4*)&sm[L_HCI + wid*32 + q*8 + 4];
    awa.f4  = *(const float4*)&AW[q*4];        // C-space: features q*4+r
    awb.f4  = *(const float4*)&AW[16 + q*4];
    cwa.f4  = *(const float4*)&CW2[q*4];
    cwb.f4  = *(const float4*)&CW2[16 + q*4];
    const float4 b2A = *(const float4*)&EB2[q*4];
    const float4 b2B = *(const float4*)&EB2[16 + q*4];
    const float4 cbA = *(const float4*)&CB1[q*4];
    const float4 cbB = *(const float4*)&CB1[16 + q*4];
    const float ab0 = AB[0];

    v2f ms2[4];
    #pragma unroll
    for (int g = 0; g < 4; ++g) ms2[g] = splat2(0.f);
    float xc0 = 0.f, xc1 = 0.f, xc2 = 0.f;

    // ---------- edge loop: 8 tiles x 16 edges ----------
    #pragma unroll 1
    for (int tl = 0; tl < 8; ++tl){
        const int e = tl * 16 + m16;
        const float valid = (e < NPE) ? 1.f : 0.f;
        const int js = (e < NPE) ? e : 126;
        const int j = js + ((js >= i) ? 1 : 0);

        const float2 dd = *(const float2*)&sgd[e*2];
        f4u hjA, hjB;
        hjA.f4 = *(const float4*)&sm[L_HCJ + j*36 + q*8];
        hjB.f4 = *(const float4*)&sm[L_HCJ + j*36 + q*8 + 4];
        const v2f d2s  = splat2(dd.x);
        const v2f ds2s = splat2(dd.y);

        // t1 (B-frag slots k=q*8+jj), packed-f32 chains
        v2f t01, t23, t45, t67;
        {
            v2f z;
            z = hcia.v2[0] + hjA.v2[0];
            z = __builtin_elementwise_fma(d2s, w64a.v2[0], z);
            z = __builtin_elementwise_fma(ds2s, w65a.v2[0], z);
            t01 = silu2(z);
            z = hcia.v2[1] + hjA.v2[1];
            z = __builtin_elementwise_fma(d2s, w64a.v2[1], z);
            z = __builtin_elementwise_fma(ds2s, w65a.v2[1], z);
            t23 = silu2(z);
            z = hcib.v2[0] + hjB.v2[0];
            z = __builtin_elementwise_fma(d2s, w64b.v2[0], z);
            z = __builtin_elementwise_fma(ds2s, w65b.v2[0], z);
            t45 = silu2(z);
            z = hcib.v2[1] + hjB.v2[1];
            z = __builtin_elementwise_fma(d2s, w64b.v2[1], z);
            z = __builtin_elementwise_fma(ds2s, w65b.v2[1], z);
            t67 = silu2(z);
        }
        v8s Bt;
        Bt[0]=f2bf(t01.x); Bt[1]=f2bf(t01.y); Bt[2]=f2bf(t23.x); Bt[3]=f2bf(t23.y);
        Bt[4]=f2bf(t45.x); Bt[5]=f2bf(t45.y); Bt[6]=f2bf(t67.x); Bt[7]=f2bf(t67.y);

        // layer 2: D[f][e]
        v4f c0 = {b2A.x, b2A.y, b2A.z, b2A.w};
        v4f c1 = {b2B.x, b2B.y, b2B.z, b2B.w};
        c0 = __builtin_amdgcn_mfma_f32_16x16x32_bf16(Aw20, Bt, c0, 0, 0, 0);
        c1 = __builtin_amdgcn_mfma_f32_16x16x32_bf16(Aw21, Bt, c1, 0, 0, 0);
        v2f sa, sb, sc, sd;
        { v2f z; z.x=c0[0]; z.y=c0[1]; sa = silu2(z); }
        { v2f z; z.x=c0[2]; z.y=c0[3]; sb = silu2(z); }
        { v2f z; z.x=c1[0]; z.y=c1[1]; sc = silu2(z); }
        { v2f z; z.x=c1[2]; z.y=c1[3]; sd = silu2(z); }

        // attention gate (C-space ordering); xor-32 hop on VALU via permlane
        v2f lgv = sa * awa.v2[0];
        lgv = __builtin_elementwise_fma(sb, awa.v2[1], lgv);
        lgv = __builtin_elementwise_fma(sc, awb.v2[0], lgv);
        lgv = __builtin_elementwise_fma(sd, awb.v2[1], lgv);
        float lg = lgv.x + lgv.y;
        lg += __shfl_xor(lg, 16, 64);
        lg = xor32_add(lg);
        const float att = sigmoidf_(lg + ab0) * valid;
        const v2f atts = splat2(att);

        const v2f g0 = sa * atts, g1 = sb * atts, g2 = sc * atts, g3 = sd * atts;
        ms2[0] += g0; ms2[1] += g1; ms2[2] += g2; ms2[3] += g3;
        v8s Bm;
        Bm[0]=f2bf(g0.x); Bm[1]=f2bf(g0.y); Bm[2]=f2bf(g1.x); Bm[3]=f2bf(g1.y);
        Bm[4]=f2bf(g2.x); Bm[5]=f2bf(g2.y); Bm[6]=f2bf(g3.x); Bm[7]=f2bf(g3.y);

        // coord head
        v4f e0 = {cbA.x, cbA.y, cbA.z, cbA.w};
        v4f e1 = {cbB.x, cbB.y, cbB.z, cbB.w};
        e0 = __builtin_amdgcn_mfma_f32_16x16x32_bf16(Ac0, Bm, e0, 0, 0, 0);
        e1 = __builtin_amdgcn_mfma_f32_16x16x32_bf16(Ac1, Bm, e1, 0, 0, 0);
        v2f ca, cb, cc, cd;
        { v2f z; z.x=e0[0]; z.y=e0[1]; ca = silu2(z); }
        { v2f z; z.x=e0[2]; z.y=e0[3]; cb = silu2(z); }
        { v2f z; z.x=e1[0]; z.y=e1[1]; cc = silu2(z); }
        { v2f z; z.x=e1[2]; z.y=e1[3]; cd = silu2(z); }
        v2f trv = ca * cwa.v2[0];
        trv = __builtin_elementwise_fma(cb, cwa.v2[1], trv);
        trv = __builtin_elementwise_fma(cc, cwb.v2[0], trv);
        trv = __builtin_elementwise_fma(cd, cwb.v2[1], trv);
        float tr = trv.x + trv.y;
        tr += __shfl_xor(tr, 16, 64);
        tr = xor32_add(tr);

        // r pre-scaled by rinv in prologue; just mask and accumulate
        const float coef = tanhf_fast(tr) * valid;
        const float rs0 = sgr[e*3 + 0];
        const float rs1 = sgr[e*3 + 1];
        const float rs2 = sgr[e*3 + 2];
        xc0 = fmaf(rs0, coef, xc0);
        xc1 = fmaf(rs1, coef, xc1);
        xc2 = fmaf(rs2, coef, xc2);
    }

    // ---------- reduce ms over the 16 edge-lanes within each quad ----------
    float msv[8] = {ms2[0].x, ms2[0].y, ms2[1].x, ms2[1].y,
                    ms2[2].x, ms2[2].y, ms2[3].x, ms2[3].y};
    #pragma unroll
    for (int jj = 0; jj < 8; ++jj){
        float v = msv[jj];
        v += __shfl_xor(v, 1, 64); v += __shfl_xor(v, 2, 64);
        v += __shfl_xor(v, 4, 64); v += __shfl_xor(v, 8, 64);
        msv[jj] = v;
    }
    // ---------- reduce xc over all 64 lanes (each edge counted 4x) ----------
    {
        float v0 = xc0, v1 = xc1, v2 = xc2;
        #pragma unroll
        for (int s = 1; s < 32; s <<= 1){
            v0 += __shfl_xor(v0, s, 64);
            v1 += __shfl_xor(v1, s, 64);
            v2 += __shfl_xor(v2, s, 64);
        }
        v0 = xor32_add(v0);
        v1 = xor32_add(v1);
        v2 = xor32_add(v2);
        xc0 = v0 * 0.25f; xc1 = v1 * 0.25f; xc2 = v2 * 0.25f;
    }

    if (lane < 3){
        const float xiv = (lane == 0) ? xi0 : ((lane == 1) ? xi1 : xi2);
        const float xcv = (lane == 0) ? xc0 : ((lane == 1) ? xc1 : xc2);
        OUT[bI*384 + i*3 + lane] = fmaf(xcv, 5.0f, xiv);
    }

    // ---------- stash ms (feature-ordered) into now-free geometry LDS ----------
    if (m16 == 0){
        #pragma unroll
        for (int jj = 0; jj < 8; ++jj){
            const int tau = (jj < 4) ? (q*4 + jj) : (16 + q*4 + (jj - 4));
            sgr[tau] = msv[jj];
        }
    }

    // ---------- node MLP ----------
    const int o = lane & 31;
    const float* hp = &Hin[node * 32];
    float a1 = NB1[o];
    #pragma unroll
    for (int k = 0; k < 32; ++k) a1 = fmaf(hp[k], NW1[k * 32 + o], a1);
    #pragma unroll
    for (int k = 0; k < 32; ++k) a1 = fmaf(sgr[k], NW1[(32 + k) * 32 + o], a1);
    const float s1v = a1 * sigmoidf_(a1);
    float a2 = NB2[o];
    #pragma unroll
    for (int k = 0; k < 32; ++k) a2 = fmaf(__shfl(s1v, k, 64), NW2[k * 32 + o], a2);
    if (lane < 32)
        OUT[49152 + node * 32 + o] = hp[o] + a2;
}

extern "C" void kernel_launch(void* const* d_in, const int* in_sizes, int n_in,
                              void* d_out, int out_size, void* d_ws, size_t ws_size,
                              hipStream_t stream) {
    (void)in_sizes; (void)n_in; (void)out_size; (void)d_ws; (void)ws_size;
    eq_gnn_fused<<<dim3(2048), dim3(512), 0, stream>>>(
        (const float*)d_in[0],  (const float*)d_in[1],  (const float*)d_in[2],
        (const float*)d_in[3],  (const float*)d_in[4],  (const float*)d_in[5],  (const float*)d_in[6],
        (const float*)d_in[7],  (const float*)d_in[8],  (const float*)d_in[9],  (const float*)d_in[10],
        (const float*)d_in[11], (const float*)d_in[12], (const float*)d_in[13],
        (const float*)d_in[14], (const float*)d_in[15],
        (float*)d_out);
}